// Round 6
// baseline (598.646 us; speedup 1.0000x reference)
//
#include <hip/hip_runtime.h>
#include <math.h>

// BinaryTreeLSTM MI355X — persistent kernel R6: L3-coherent state, light barriers.
// R5 post-mortem: 2x __threadfence per block per barrier (wbl2+inv) cost ~19us
// per level transition (L2 flush of state + weight-cache invalidation).
// R6: all tree state (c fp32, h bf16) moves via agent-scope relaxed atomics
// (L1/L2-bypass -> L3, which is memory-side coherent across XCDs). Barriers
// need NO fences (syncthreads drains vmcnt; store-ack = L3-visible). Weights
// stay L2-cached and never invalidated. Tail levels B<=64 run in block 0 with
// __syncthreads only. Grid barriers: 14 -> 8 (1 heavy post-prep + 7 light).
//
// Math identical to R3..R5: h_prev (B,512) = [lh|rh] => one GEMM/level,
// G = h_view @ [Wl|Wr]^T + bias5 (bias5 folds pad_xg; pad chunk2 -> lf AND rf).
// MFMA 16x16x32 bf16 fp32-acc; weight frag f=((kc*16+grp)*NG+g), b128/lane.

#define MEM 256
#define NBLK 256
#define NTHR 1024
#define NWAVE (NBLK * 16)

typedef __attribute__((ext_vector_type(8))) short bf16x8;
typedef __attribute__((ext_vector_type(4))) float f32x4;

__device__ __forceinline__ float sigf(float x) { return 1.0f / (1.0f + __expf(-x)); }

__device__ __forceinline__ unsigned short f2b(float f) {
  unsigned int u = __float_as_uint(f);
  u = (u + 0x7FFFu + ((u >> 16) & 1u)) >> 16;
  return (unsigned short)u;
}

// ---- L3-coherent (agent-scope, L1/L2-bypass) state accessors ----
__device__ __forceinline__ unsigned long long ald64(const unsigned short* p) {
  return __hip_atomic_load((unsigned long long*)p, __ATOMIC_RELAXED,
                           __HIP_MEMORY_SCOPE_AGENT);
}
__device__ __forceinline__ float aldf(const float* p) {
  return __hip_atomic_load((float*)p, __ATOMIC_RELAXED, __HIP_MEMORY_SCOPE_AGENT);
}
__device__ __forceinline__ void astf(float* p, float v) {
  __hip_atomic_store(p, v, __ATOMIC_RELAXED, __HIP_MEMORY_SCOPE_AGENT);
}
__device__ __forceinline__ void ast16(unsigned short* p, unsigned short v) {
  __hip_atomic_store(p, v, __ATOMIC_RELAXED, __HIP_MEMORY_SCOPE_AGENT);
}

// Flag barrier; heavy=true adds release fences for normal-stored (prep) data.
// done blocks post 0xFFFFFFFF (passes all future targets) and skip the wait.
__device__ __forceinline__ void gridbar(unsigned* flags, unsigned* gen,
                                        unsigned target, bool done, bool heavy) {
  __syncthreads();  // drains all waves' vm ops (bypass stores acked at L3)
  if (blockIdx.x == 0) {
    if (threadIdx.x >= 1 && threadIdx.x < NBLK) {
      while (__hip_atomic_load(flags + threadIdx.x * 32, __ATOMIC_RELAXED,
                               __HIP_MEMORY_SCOPE_AGENT) < target)
        __builtin_amdgcn_s_sleep(1);
    }
    __syncthreads();  // all flags observed
    if (threadIdx.x == 0) {
      if (heavy) __threadfence();  // release block 0's prep stores
      __hip_atomic_store(gen, target, __ATOMIC_RELAXED, __HIP_MEMORY_SCOPE_AGENT);
    }
    __syncthreads();
  } else {
    if (threadIdx.x == 0) {
      if (heavy) __threadfence();  // release this block's prep stores
      __hip_atomic_store(flags + blockIdx.x * 32, done ? 0xFFFFFFFFu : target,
                         __ATOMIC_RELAXED, __HIP_MEMORY_SCOPE_AGENT);
      if (!done) {
        while (__hip_atomic_load(gen, __ATOMIC_RELAXED,
                                 __HIP_MEMORY_SCOPE_AGENT) < target)
          __builtin_amdgcn_s_sleep(1);
      }
    }
    __syncthreads();
  }
}

// One compose task: 16x16 output tile `tile`, column group `grp` (from t).
__device__ __forceinline__ void compose_task(
    int t, int tmask, int ts, int B, bool last,
    const unsigned short* hs, const float* cs,
    const unsigned short* __restrict__ Wcf, const float* __restrict__ bias5,
    float* dc, unsigned short* dh, float* out, int m, int quad, int lane) {
  int tile = t & tmask;
  int grp = t >> ts;
  int row_a = tile * 16 + m;
  bool a_ok = (row_a < B);
  f32x4 acc0 = {0.f, 0.f, 0.f, 0.f}, acc1 = acc0, acc2 = acc0, acc3 = acc0,
        acc4 = acc0;
  const unsigned short* arow = hs + row_a * 512 + quad * 8;
#pragma unroll
  for (int kc = 0; kc < 16; kc++) {
    union { unsigned long long q[2]; bf16x8 v; } au;
    au.q[0] = 0; au.q[1] = 0;
    if (a_ok) {
      au.q[0] = ald64(arow + kc * 32);
      au.q[1] = ald64(arow + kc * 32 + 4);
    }
    const unsigned short* bp = Wcf + ((kc * 16 + grp) * 5) * 512 + lane * 8;
    bf16x8 b0 = *(const bf16x8*)(bp);
    bf16x8 b1 = *(const bf16x8*)(bp + 512);
    bf16x8 b2 = *(const bf16x8*)(bp + 1024);
    bf16x8 b3 = *(const bf16x8*)(bp + 1536);
    bf16x8 b4 = *(const bf16x8*)(bp + 2048);
    acc0 = __builtin_amdgcn_mfma_f32_16x16x32_bf16(au.v, b0, acc0, 0, 0, 0);
    acc1 = __builtin_amdgcn_mfma_f32_16x16x32_bf16(au.v, b1, acc1, 0, 0, 0);
    acc2 = __builtin_amdgcn_mfma_f32_16x16x32_bf16(au.v, b2, acc2, 0, 0, 0);
    acc3 = __builtin_amdgcn_mfma_f32_16x16x32_bf16(au.v, b3, acc3, 0, 0, 0);
    acc4 = __builtin_amdgcn_mfma_f32_16x16x32_bf16(au.v, b4, acc4, 0, 0, 0);
  }
  int col = grp * 16 + m;
  float b0 = bias5[col], b1 = bias5[256 + col], b2 = bias5[512 + col];
  float b3 = bias5[768 + col], b4 = bias5[1024 + col];
#pragma unroll
  for (int reg = 0; reg < 4; reg++) {
    int row = tile * 16 + quad * 4 + reg;
    if (row >= B) continue;
    float u = tanhf(acc0[reg] + b0);
    float ig = sigf(acc1[reg] + b1);
    float lf = sigf(acc2[reg] + b2);
    float rf = sigf(acc3[reg] + b3);
    float o = sigf(acc4[reg] + b4);
    float lc = aldf(cs + (2 * row) * MEM + col);
    float rc = aldf(cs + (2 * row + 1) * MEM + col);
    float c = ig * u + lf * lc + rf * rc;
    float h = o * tanhf(c);
    astf(dc + row * MEM + col, c);
    ast16(dh + row * MEM + col, f2b(h));
    if (last) astf(out + 256 + col, h);
  }
}

__global__ __launch_bounds__(NTHR, 1) void k_tree(
    const float* embs, const float* Wx, const float* bx,
    const float* Wl, const float* Wr, const float* emb_last,
    unsigned short* Wcf, unsigned short* Wxf, unsigned short* eb,
    float* bias5, float* cA, float* cB, unsigned short* hA, unsigned short* hB,
    float* out, unsigned* flags, unsigned* gen) {
  const int tid = threadIdx.x;
  const int lane = tid & 63;
  const int wave = tid >> 6;
  const int wave_id = blockIdx.x * 16 + wave;
  const int gtid = blockIdx.x * NTHR + tid;
  const int m = lane & 15, quad = lane >> 4;
  unsigned target = 0;

  // ---------------- Phase 0: prep (normal stores; heavy barrier after) ------
  for (int idx = gtid; idx < 1280 * 512; idx += NBLK * NTHR) {  // Wcf
    int f = idx >> 9, r = idx & 511;
    int l8 = r >> 3, j = r & 7;
    int gate = f % 5, t = f / 5;
    int grp = t & 15, kc = t >> 4;
    int k = kc * 32 + ((l8 >> 4) << 3) + j;
    int n = gate * 256 + (grp << 4) + (l8 & 15);
    float v = (k < 256) ? Wl[n * 256 + k] : Wr[n * 256 + (k - 256)];
    Wcf[idx] = f2b(v);
  }
  for (int idx = gtid; idx < 480 * 512; idx += NBLK * NTHR) {  // Wxf
    int f = idx >> 9, r = idx & 511;
    int l8 = r >> 3, j = r & 7;
    int gate = f % 3, t = f / 3;
    int grp = t & 15, kc = t >> 4;
    int k = kc * 32 + ((l8 >> 4) << 3) + j;
    const int gmap[3] = {0, 1, 3};
    int n = gmap[gate] * 256 + (grp << 4) + (l8 & 15);
    float v = (k < 300) ? Wx[n * 300 + k] : 0.0f;
    Wxf[idx] = f2b(v);
  }
  for (int idx = gtid; idx < 8192 * 320; idx += NBLK * NTHR) {  // embs->bf16
    int row = idx / 320;
    int k = idx - row * 320;
    eb[idx] = (k < 300) ? f2b(embs[row * 300 + k]) : (unsigned short)0;
  }
  if (gtid < 1280) {  // bias5 = pad_xg (gate-mapped) + bx folded
    const int map5[5] = {0, 1, 2, 2, 3};
    int g = gtid >> 8, j = gtid & 255;
    int wrow = map5[g] * 256 + j;
    const float* w = Wx + wrow * 300;
    float s = bx[wrow];
    for (int k = 0; k < 300; k++) s += emb_last[k] * w[k];
    bias5[gtid] = s;
  }
  gridbar(flags, gen, ++target, false, true);  // heavy: flush prep to L3

  // ---------------- Phase 1: leaf (8192 tasks; state stores -> L3) ---------
  for (int t = wave_id; t < 8192; t += NWAVE) {
    int tile = t & 511;
    int grp = t >> 9;
    int row_a = tile * 16 + m;
    f32x4 acc0 = {0.f, 0.f, 0.f, 0.f}, acc1 = acc0, acc2 = acc0;
    const unsigned short* arow = eb + row_a * 320 + quad * 8;
#pragma unroll
    for (int kc = 0; kc < 10; kc++) {
      bf16x8 a = *(const bf16x8*)(arow + kc * 32);
      const unsigned short* bp = Wxf + ((kc * 16 + grp) * 3) * 512 + lane * 8;
      bf16x8 b0 = *(const bf16x8*)(bp);
      bf16x8 b1 = *(const bf16x8*)(bp + 512);
      bf16x8 b2 = *(const bf16x8*)(bp + 1024);
      acc0 = __builtin_amdgcn_mfma_f32_16x16x32_bf16(a, b0, acc0, 0, 0, 0);
      acc1 = __builtin_amdgcn_mfma_f32_16x16x32_bf16(a, b1, acc1, 0, 0, 0);
      acc2 = __builtin_amdgcn_mfma_f32_16x16x32_bf16(a, b2, acc2, 0, 0, 0);
    }
    int col = grp * 16 + m;
    float b0 = bx[col], b1 = bx[256 + col], b3 = bx[768 + col];
#pragma unroll
    for (int reg = 0; reg < 4; reg++) {
      int row = tile * 16 + quad * 4 + reg;
      float u = tanhf(acc0[reg] + b0);
      float ig = sigf(acc1[reg] + b1);
      float o = sigf(acc2[reg] + b3);
      float c = ig * u;
      astf(cA + row * MEM + col, c);
      ast16(hA + row * MEM + col, f2b(o * tanhf(c)));
    }
  }
  gridbar(flags, gen, ++target, false, false);

  // ---------------- Phase 2: tree levels ----------------
  const float* cs = cA;
  const unsigned short* hs = hA;
  int B = 4096, ts = 8, lvl = 0;
  while (B >= 1) {
    bool tail = (B <= 64);  // block 0 only, __syncthreads-synced
    bool last = (B == 1);
    float* dc;
    unsigned short* dh;
    if (last) {
      dc = out;  // out[col] = c via compose_task's dc store
      dh = hB;   // dummy sink
    } else if ((lvl & 1) == 0) {
      dc = cB; dh = hB;
    } else {
      dc = cA; dh = hA;
    }
    int tiles = (B >= 16) ? (B >> 4) : 1;
    int tmask = tiles - 1;
    int ntask = tiles * 16;
    if (!tail) {
      for (int t = wave_id; t < ntask; t += NWAVE)
        compose_task(t, tmask, ts, B, last, hs, cs, Wcf, bias5, dc, dh, out,
                     m, quad, lane);
      // retire blocks not needed at any later level (next needs tiles/2 blocks;
      // after B=128 only block 0 continues into the tail)
      bool done = (blockIdx.x > 0) &&
                  ((B == 128) || ((int)blockIdx.x >= (tiles >> 1)));
      gridbar(flags, gen, ++target, done, false);
      if (done) return;
    } else {
      for (int t = wave; t < ntask; t += 16)
        compose_task(t, tmask, ts, B, last, hs, cs, Wcf, bias5, dc, dh, out,
                     m, quad, lane);
      __syncthreads();
    }
    cs = dc;
    hs = dh;
    B >>= 1;
    if (ts > 0) ts--;
    lvl++;
  }
}

extern "C" void kernel_launch(void* const* d_in, const int* in_sizes, int n_in,
                              void* d_out, int out_size, void* d_ws, size_t ws_size,
                              hipStream_t stream) {
  const float* embs = (const float*)d_in[0];
  const float* Wx = (const float*)d_in[1];
  const float* bx = (const float*)d_in[2];
  const float* Wl = (const float*)d_in[3];
  const float* Wr = (const float*)d_in[4];
  const float* emb_table = (const float*)d_in[5];
  float* out = (float*)d_out;

  // Workspace: [0,4) gen | [128, 128+256*128) flags | data from 64KB (~25MB)
  unsigned* gen = (unsigned*)d_ws;
  unsigned* flags = (unsigned*)((char*)d_ws + 128);
  float* base = (float*)((char*)d_ws + 65536);
  float* cA = base;                              // 8192*256 f32
  float* cB = cA + 8192 * 256;                   // 4096*256 f32
  float* bias5 = cB + 4096 * 256;                // 1280 f32
  unsigned short* hA = (unsigned short*)(bias5 + 1280);  // 8192*256 bf16
  unsigned short* hB = hA + 8192 * 256;                  // 4096*256 bf16
  unsigned short* Wcf = hB + 4096 * 256;                 // 1280*512
  unsigned short* Wxf = Wcf + 1280 * 512;                // 480*512
  unsigned short* eb = Wxf + 480 * 512;                  // 8192*320

  hipMemsetAsync(d_ws, 0, 65536, stream);  // zero gen+flags (ws is poisoned)

  k_tree<<<NBLK, NTHR, 0, stream>>>(
      embs, Wx, bx, Wl, Wr, emb_table + (in_sizes[5] - 300),
      Wcf, Wxf, eb, bias5, cA, cB, hA, hB, out, flags, gen);
}

// Round 7
// 452.374 us; speedup vs baseline: 1.3233x; 1.3233x over previous
//
#include <hip/hip_runtime.h>
#include <math.h>

// BinaryTreeLSTM MI355X — R7: persistent kernel, fence-free coherence.
// R5: fenced barriers cost ~18us each (buffer_wbl2+buffer_inv scan the 4MiB
// XCD L2 and evict weights every level). R6: atomics everywhere = slow
// (unvectorized, serialized, L3 latency on hot paths).
// R7: state (c,h) crosses blocks via sc0|sc1 write-through stores + bypass
// loads (L3 = coherence point, no dirty L2 => no wbl2, no inv), implemented
// as batched inline-asm dwordx4 with ONE s_waitcnt per task. Weights are
// bypass-written once in prep, then PLAIN cached loads forever (kernel-start
// caches are clean; never rewritten => never stale, never invalidated).
// Barriers = pure flag barriers (no fences), gen broadcast on 8 lines.
//
// Math identical R3..R6: h_prev (B,512)=[lh|rh] => one GEMM/level,
// G = h_view @ [Wl|Wr]^T + bias5 (bias5 folds pad_xg; pad chunk2 -> lf AND
// rf). MFMA 16x16x32 bf16 fp32-acc; c fp32 state, h bf16 state.
// Weight frag f=((kc*16+grp)*NG+g): elem[lane*8+j]=W[k=kc*32+(lane>>4)*8+j]
// [n=g*256+grp*16+(lane&15)] -> b_frag = coalesced plain b128, L1/L2-hot.

#define MEM 256
#define NBLK 256
#define NTHR 1024
#define NWAVE (NBLK * 16)

typedef __attribute__((ext_vector_type(8))) short bf16x8;
typedef __attribute__((ext_vector_type(4))) float f32x4;

__device__ __forceinline__ float sigf(float x) { return 1.0f / (1.0f + __expf(-x)); }

__device__ __forceinline__ unsigned short f2b(float f) {
  unsigned int u = __float_as_uint(f);
  u = (u + 0x7FFFu + ((u >> 16) & 1u)) >> 16;
  return (unsigned short)u;
}

// ---- L3 write-through stores (no L2 dirty lines) ----
__device__ __forceinline__ void st_f32(float* p, float v) {
  asm volatile("global_store_dword %0, %1, off sc0 sc1" :: "v"(p), "v"(v) : "memory");
}
__device__ __forceinline__ void st_u16(unsigned short* p, unsigned v) {
  asm volatile("global_store_short %0, %1, off sc0 sc1" :: "v"(p), "v"(v) : "memory");
}
__device__ __forceinline__ void drain() {
  asm volatile("s_waitcnt vmcnt(0)" ::: "memory");
}

// Pure flag barrier, NO cache fences. flags[b*32] = block b's line.
// gen broadcast over 8 lines. Monotone targets; done blocks post 0xFFFFFFFF.
__device__ __forceinline__ void gridbar(unsigned* flags, unsigned* gen,
                                        unsigned target, bool done) {
  drain();  // all bypass stores acked at L3 before signaling
  __syncthreads();
  if (blockIdx.x == 0) {
    if (threadIdx.x >= 1 && threadIdx.x < NBLK) {
      while (__hip_atomic_load(flags + threadIdx.x * 32, __ATOMIC_RELAXED,
                               __HIP_MEMORY_SCOPE_AGENT) < target)
        __builtin_amdgcn_s_sleep(2);
    }
    __syncthreads();
    if (threadIdx.x < 8)
      __hip_atomic_store(gen + threadIdx.x * 32, target, __ATOMIC_RELAXED,
                         __HIP_MEMORY_SCOPE_AGENT);
    __syncthreads();
  } else {
    if (threadIdx.x == 0) {
      __hip_atomic_store(flags + blockIdx.x * 32, done ? 0xFFFFFFFFu : target,
                         __ATOMIC_RELAXED, __HIP_MEMORY_SCOPE_AGENT);
      if (!done) {
        unsigned* g = gen + (blockIdx.x & 7) * 32;
        while (__hip_atomic_load(g, __ATOMIC_RELAXED,
                                 __HIP_MEMORY_SCOPE_AGENT) < target)
          __builtin_amdgcn_s_sleep(2);
      }
    }
    __syncthreads();
  }
}

// One compose task: output tile (16 rows) x column group grp (16 cols x5 gates)
__device__ __forceinline__ void compose_task(
    int t, int tmask, int ts, int B, bool last,
    const unsigned short* hs, const float* cs,
    const unsigned short* __restrict__ Wcf, const float* __restrict__ bias5,
    float* dc, unsigned short* dh, float* out, int m, int quad, int lane) {
  int tile = t & tmask;
  int grp = t >> ts;
  int row_a = tile * 16 + m;
  if (row_a >= B) row_a = B - 1;  // only for B<16; dup rows, outputs guarded

  // Prefetch c-state (bypass, no wait yet): lc/rc for 4 regs
  const float* cb0 = cs + (2 * (tile * 16 + quad * 4)) * MEM + grp * 16 + m;
  const float* cb2 = cb0 + 1024;  // + 4 rows of c
  float lc0, rc0, lc1, rc1, lc2, rc2, lc3, rc3;
  asm volatile(
      "global_load_dword %0, %8, off sc0 sc1\n\t"
      "global_load_dword %1, %8, off offset:1024 sc0 sc1\n\t"
      "global_load_dword %2, %8, off offset:2048 sc0 sc1\n\t"
      "global_load_dword %3, %8, off offset:3072 sc0 sc1\n\t"
      "global_load_dword %4, %9, off sc0 sc1\n\t"
      "global_load_dword %5, %9, off offset:1024 sc0 sc1\n\t"
      "global_load_dword %6, %9, off offset:2048 sc0 sc1\n\t"
      "global_load_dword %7, %9, off offset:3072 sc0 sc1"
      : "=v"(lc0), "=v"(rc0), "=v"(lc1), "=v"(rc1),
        "=v"(lc2), "=v"(rc2), "=v"(lc3), "=v"(rc3)
      : "v"(cb0), "v"(cb2) : "memory");

  // A-fragments for all 16 kc (bypass, batched), single wait covers c too
  const unsigned short* arow = hs + row_a * 512 + quad * 8;
  f32x4 a0, a1, a2, a3, a4, a5, a6, a7, a8, a9, a10, a11, a12, a13, a14, a15;
  asm volatile(
      "global_load_dwordx4 %0, %16, off sc0 sc1\n\t"
      "global_load_dwordx4 %1, %16, off offset:64 sc0 sc1\n\t"
      "global_load_dwordx4 %2, %16, off offset:128 sc0 sc1\n\t"
      "global_load_dwordx4 %3, %16, off offset:192 sc0 sc1\n\t"
      "global_load_dwordx4 %4, %16, off offset:256 sc0 sc1\n\t"
      "global_load_dwordx4 %5, %16, off offset:320 sc0 sc1\n\t"
      "global_load_dwordx4 %6, %16, off offset:384 sc0 sc1\n\t"
      "global_load_dwordx4 %7, %16, off offset:448 sc0 sc1\n\t"
      "global_load_dwordx4 %8, %16, off offset:512 sc0 sc1\n\t"
      "global_load_dwordx4 %9, %16, off offset:576 sc0 sc1\n\t"
      "global_load_dwordx4 %10, %16, off offset:640 sc0 sc1\n\t"
      "global_load_dwordx4 %11, %16, off offset:704 sc0 sc1\n\t"
      "global_load_dwordx4 %12, %16, off offset:768 sc0 sc1\n\t"
      "global_load_dwordx4 %13, %16, off offset:832 sc0 sc1\n\t"
      "global_load_dwordx4 %14, %16, off offset:896 sc0 sc1\n\t"
      "global_load_dwordx4 %15, %16, off offset:960 sc0 sc1\n\t"
      "s_waitcnt vmcnt(0)"
      : "=v"(a0), "=v"(a1), "=v"(a2), "=v"(a3), "=v"(a4), "=v"(a5),
        "=v"(a6), "=v"(a7), "=v"(a8), "=v"(a9), "=v"(a10), "=v"(a11),
        "=v"(a12), "=v"(a13), "=v"(a14), "=v"(a15)
      : "v"(arow) : "memory");
  f32x4 af[16] = {a0, a1, a2, a3, a4, a5, a6, a7,
                  a8, a9, a10, a11, a12, a13, a14, a15};

  f32x4 acc0 = {0.f, 0.f, 0.f, 0.f}, acc1 = acc0, acc2 = acc0, acc3 = acc0,
        acc4 = acc0;
#pragma unroll
  for (int kc = 0; kc < 16; kc++) {
    bf16x8 a = __builtin_bit_cast(bf16x8, af[kc]);
    const unsigned short* bp = Wcf + ((kc * 16 + grp) * 5) * 512 + lane * 8;
    bf16x8 b0 = *(const bf16x8*)(bp);
    bf16x8 b1 = *(const bf16x8*)(bp + 512);
    bf16x8 b2 = *(const bf16x8*)(bp + 1024);
    bf16x8 b3 = *(const bf16x8*)(bp + 1536);
    bf16x8 b4 = *(const bf16x8*)(bp + 2048);
    acc0 = __builtin_amdgcn_mfma_f32_16x16x32_bf16(a, b0, acc0, 0, 0, 0);
    acc1 = __builtin_amdgcn_mfma_f32_16x16x32_bf16(a, b1, acc1, 0, 0, 0);
    acc2 = __builtin_amdgcn_mfma_f32_16x16x32_bf16(a, b2, acc2, 0, 0, 0);
    acc3 = __builtin_amdgcn_mfma_f32_16x16x32_bf16(a, b3, acc3, 0, 0, 0);
    acc4 = __builtin_amdgcn_mfma_f32_16x16x32_bf16(a, b4, acc4, 0, 0, 0);
  }
  int col = grp * 16 + m;
  float b0s = bias5[col], b1s = bias5[256 + col], b2s = bias5[512 + col];
  float b3s = bias5[768 + col], b4s = bias5[1024 + col];
  float lcs[4] = {lc0, lc1, lc2, lc3};
  float rcs[4] = {rc0, rc1, rc2, rc3};
#pragma unroll
  for (int reg = 0; reg < 4; reg++) {
    int row = tile * 16 + quad * 4 + reg;
    if (row >= B) continue;
    float u = tanhf(acc0[reg] + b0s);
    float ig = sigf(acc1[reg] + b1s);
    float lf = sigf(acc2[reg] + b2s);
    float rf = sigf(acc3[reg] + b3s);
    float o = sigf(acc4[reg] + b4s);
    float c = ig * u + lf * lcs[reg] + rf * rcs[reg];
    float h = o * tanhf(c);
    st_f32(dc + row * MEM + col, c);
    st_u16(dh + row * MEM + col, f2b(h));
    if (last) st_f32(out + 256 + col, h);
  }
}

__global__ __launch_bounds__(NTHR, 1) void k_tree(
    const float* embs, const float* Wx, const float* bx,
    const float* Wl, const float* Wr, const float* emb_last,
    unsigned short* Wcf, unsigned short* Wxf, unsigned short* eb,
    float* bias5, float* cA, float* cB, unsigned short* hA, unsigned short* hB,
    float* out, unsigned* flags, unsigned* gen) {
  const int tid = threadIdx.x;
  const int lane = tid & 63;
  const int wave = tid >> 6;
  const int wave_id = blockIdx.x * 16 + wave;
  const int gtid = blockIdx.x * NTHR + tid;
  const int m = lane & 15, quad = lane >> 4;
  unsigned target = 0;

  // ---- Phase 0: prep. Plain cached reads of inputs (clean caches at kernel
  // start), bypass write-through stores of outputs (no dirty L2 anywhere). ----
  for (int idx = gtid; idx < 1280 * 512; idx += NBLK * NTHR) {  // Wcf
    int f = idx >> 9, r = idx & 511;
    int l8 = r >> 3, j = r & 7;
    int gate = f % 5, t = f / 5;
    int grp = t & 15, kc = t >> 4;
    int k = kc * 32 + ((l8 >> 4) << 3) + j;
    int n = gate * 256 + (grp << 4) + (l8 & 15);
    float v = (k < 256) ? Wl[n * 256 + k] : Wr[n * 256 + (k - 256)];
    st_u16(Wcf + idx, f2b(v));
  }
  for (int idx = gtid; idx < 480 * 512; idx += NBLK * NTHR) {  // Wxf
    int f = idx >> 9, r = idx & 511;
    int l8 = r >> 3, j = r & 7;
    int gate = f % 3, t = f / 3;
    int grp = t & 15, kc = t >> 4;
    int k = kc * 32 + ((l8 >> 4) << 3) + j;
    const int gmap[3] = {0, 1, 3};
    int n = gmap[gate] * 256 + (grp << 4) + (l8 & 15);
    float v = (k < 300) ? Wx[n * 300 + k] : 0.0f;
    st_u16(Wxf + idx, f2b(v));
  }
  for (int idx = gtid; idx < 8192 * 320; idx += NBLK * NTHR) {  // embs->bf16
    int row = idx / 320;
    int k = idx - row * 320;
    st_u16(eb + idx, (k < 300) ? f2b(embs[row * 300 + k]) : 0u);
  }
  if (gtid < 1280) {  // bias5 = pad_xg (gate-mapped) + bx folded
    const int map5[5] = {0, 1, 2, 2, 3};
    int g = gtid >> 8, j = gtid & 255;
    int wrow = map5[g] * 256 + j;
    const float* w = Wx + wrow * 300;
    float s = bx[wrow];
    for (int k = 0; k < 300; k++) s += emb_last[k] * w[k];
    st_f32(bias5 + gtid, s);
  }
  gridbar(flags, gen, ++target, false);

  // ---- Phase 1: leaf. eb/Wxf plain cached reads; state out via bypass. ----
  for (int t = wave_id; t < 8192; t += NWAVE) {
    int tile = t & 511;
    int grp = t >> 9;
    int row_a = tile * 16 + m;
    f32x4 acc0 = {0.f, 0.f, 0.f, 0.f}, acc1 = acc0, acc2 = acc0;
    const unsigned short* arow = eb + row_a * 320 + quad * 8;
#pragma unroll
    for (int kc = 0; kc < 10; kc++) {
      bf16x8 a = *(const bf16x8*)(arow + kc * 32);
      const unsigned short* bp = Wxf + ((kc * 16 + grp) * 3) * 512 + lane * 8;
      bf16x8 b0 = *(const bf16x8*)(bp);
      bf16x8 b1 = *(const bf16x8*)(bp + 512);
      bf16x8 b2 = *(const bf16x8*)(bp + 1024);
      acc0 = __builtin_amdgcn_mfma_f32_16x16x32_bf16(a, b0, acc0, 0, 0, 0);
      acc1 = __builtin_amdgcn_mfma_f32_16x16x32_bf16(a, b1, acc1, 0, 0, 0);
      acc2 = __builtin_amdgcn_mfma_f32_16x16x32_bf16(a, b2, acc2, 0, 0, 0);
    }
    int col = grp * 16 + m;
    float b0 = bx[col], b1 = bx[256 + col], b3 = bx[768 + col];
#pragma unroll
    for (int reg = 0; reg < 4; reg++) {
      int row = tile * 16 + quad * 4 + reg;
      float u = tanhf(acc0[reg] + b0);
      float ig = sigf(acc1[reg] + b1);
      float o = sigf(acc2[reg] + b3);
      float c = ig * u;
      st_f32(cA + row * MEM + col, c);
      st_u16(hA + row * MEM + col, f2b(o * tanhf(c)));
    }
  }
  gridbar(flags, gen, ++target, false);

  // ---- Phase 2: 13 tree levels, column-sliced, flag barriers only ----
  const float* cs = cA;
  const unsigned short* hs = hA;
  int B = 4096, ts = 8, lvl = 0;
  while (true) {
    bool last = (B == 1);
    float* dc;
    unsigned short* dh;
    if (last) {
      dc = out;  // out[col] = c
      dh = hB;   // dummy sink
    } else if ((lvl & 1) == 0) {
      dc = cB; dh = hB;
    } else {
      dc = cA; dh = hA;
    }
    int tiles = (B >= 16) ? (B >> 4) : 1;
    int tmask = tiles - 1;
    int ntask = tiles * 16;
    for (int t = wave_id; t < ntask; t += NWAVE)
      compose_task(t, tmask, ts, B, last, hs, cs, Wcf, bias5, dc, dh, out,
                   m, quad, lane);
    if (last) break;
    // retire blocks with no tasks at any later level
    int Bn = B >> 1;
    int fut = ((Bn >= 16) ? (Bn >> 4) : 1) * 16;
    bool done = (blockIdx.x > 0) && ((int)blockIdx.x * 16 >= fut);
    gridbar(flags, gen, ++target, done);
    if (done) return;
    cs = dc;
    hs = dh;
    B = Bn;
    if (ts > 0) ts--;
    lvl++;
  }
  drain();
}

extern "C" void kernel_launch(void* const* d_in, const int* in_sizes, int n_in,
                              void* d_out, int out_size, void* d_ws, size_t ws_size,
                              hipStream_t stream) {
  const float* embs = (const float*)d_in[0];
  const float* Wx = (const float*)d_in[1];
  const float* bx = (const float*)d_in[2];
  const float* Wl = (const float*)d_in[3];
  const float* Wr = (const float*)d_in[4];
  const float* emb_table = (const float*)d_in[5];
  float* out = (float*)d_out;

  // Workspace: [0,1KB) gen lines | [4KB,36KB) flags | data from 64KB (~25MB)
  unsigned* gen = (unsigned*)d_ws;
  unsigned* flags = (unsigned*)((char*)d_ws + 4096);
  float* base = (float*)((char*)d_ws + 65536);
  float* cA = base;                              // 8192*256 f32
  float* cB = cA + 8192 * 256;                   // 4096*256 f32
  float* bias5 = cB + 4096 * 256;                // 1280 f32
  unsigned short* hA = (unsigned short*)(bias5 + 1280);  // 8192*256 bf16
  unsigned short* hB = hA + 8192 * 256;                  // 4096*256 bf16
  unsigned short* Wcf = hB + 4096 * 256;                 // 1280*512
  unsigned short* Wxf = Wcf + 1280 * 512;                // 480*512
  unsigned short* eb = Wxf + 480 * 512;                  // 8192*320

  hipMemsetAsync(d_ws, 0, 65536, stream);  // zero gen+flags (ws is poisoned)

  k_tree<<<NBLK, NTHR, 0, stream>>>(
      embs, Wx, bx, Wl, Wr, emb_table + (in_sizes[5] - 300),
      Wcf, Wxf, eb, bias5, cA, cB, hA, hB, out, flags, gen);
}

// Round 8
// 428.100 us; speedup vs baseline: 1.3984x; 1.0567x over previous
//
#include <hip/hip_runtime.h>
#include <math.h>

// BinaryTreeLSTM MI355X — R8: persistent kernel, tile-granular DATAFLOW.
// R5/R7 evidence: grid-wide sync points cost ~20us each regardless of fence
// strategy (R5 fenced 295us vs R7 fence-free 358us; both ~60us of work +
// ~14 syncs). R8 removes 13 of 14 barriers: per-tile completion counters
// (64B line each). Producer: stores (sc0|sc1 write-through, L3-coherent) ->
// s_waitcnt vmcnt(0) -> atomicAdd(cnt[tile]). Consumer (tile tt, level l+1)
// spins until cnt_l[2tt]>=16 && cnt_l[2tt+1]>=16. Levels overlap (wavefront);
// deadlock-free: level order per wave, all 256 blocks resident (1/CU).
// One grid barrier remains (post-prep weights). Weights/eb/bias5: bypass-
// written once, plain cached reads forever (caches invalidated at dispatch).
//
// Math identical R3..R7: h_prev (B,512)=[lh|rh] => one GEMM/level,
// G = h_view @ [Wl|Wr]^T + bias5 (bias5 folds pad_xg; pad chunk2 -> lf AND
// rf). MFMA 16x16x32 bf16 fp32-acc; c fp32 state, h bf16 state.
// Weight frag f=((kc*16+grp)*NG+g): elem[lane*8+j]=W[k=kc*32+(lane>>4)*8+j]
// [n=g*256+grp*16+(lane&15)] -> b_frag = coalesced plain b128, L1/L2-hot.

#define MEM 256
#define NBLK 256
#define NTHR 1024
#define NWAVE (NBLK * 16)

typedef __attribute__((ext_vector_type(8))) short bf16x8;
typedef __attribute__((ext_vector_type(4))) float f32x4;

__device__ __forceinline__ float sigf(float x) { return 1.0f / (1.0f + __expf(-x)); }

__device__ __forceinline__ unsigned short f2b(float f) {
  unsigned int u = __float_as_uint(f);
  u = (u + 0x7FFFu + ((u >> 16) & 1u)) >> 16;
  return (unsigned short)u;
}

// ---- L3 write-through stores (no dirty L2) + drain ----
__device__ __forceinline__ void st_f32(float* p, float v) {
  asm volatile("global_store_dword %0, %1, off sc0 sc1" :: "v"(p), "v"(v) : "memory");
}
__device__ __forceinline__ void st_u16(unsigned short* p, unsigned v) {
  asm volatile("global_store_short %0, %1, off sc0 sc1" :: "v"(p), "v"(v) : "memory");
}
__device__ __forceinline__ void drain() {
  asm volatile("s_waitcnt vmcnt(0)" ::: "memory");
}
__device__ __forceinline__ unsigned ald(const unsigned* p) {
  return __hip_atomic_load((unsigned*)p, __ATOMIC_RELAXED, __HIP_MEMORY_SCOPE_AGENT);
}

// One-shot post-prep flag barrier (R7 style, no fences needed: all prep
// stores are write-through and drained before signaling).
__device__ __forceinline__ void gridbar(unsigned* flags, unsigned* gen) {
  drain();
  __syncthreads();
  if (blockIdx.x == 0) {
    if (threadIdx.x >= 1 && threadIdx.x < NBLK) {
      while (ald(flags + threadIdx.x * 32) < 1u) __builtin_amdgcn_s_sleep(2);
    }
    __syncthreads();
    if (threadIdx.x < 8)
      __hip_atomic_store(gen + threadIdx.x * 32, 1u, __ATOMIC_RELAXED,
                         __HIP_MEMORY_SCOPE_AGENT);
    __syncthreads();
  } else {
    if (threadIdx.x == 0) {
      __hip_atomic_store(flags + blockIdx.x * 32, 1u, __ATOMIC_RELAXED,
                         __HIP_MEMORY_SCOPE_AGENT);
      unsigned* g = gen + (blockIdx.x & 7) * 32;
      while (ald(g) < 1u) __builtin_amdgcn_s_sleep(2);
    }
    __syncthreads();
  }
}

// Compose task: poll 2 producer counters, then 16x16 tile x grp (5 gates).
__device__ __forceinline__ void compose_task(
    int tile, int grp, int B, bool last,
    const unsigned short* hs, const float* cs,
    const unsigned short* __restrict__ Wcf, const float* __restrict__ bias5,
    float* dc, unsigned short* dh, float* out,
    const unsigned* cp0, const unsigned* cp1, unsigned* cprod,
    int m, int quad, int lane) {
  // Wait for both source tiles (h rows [32t,32t+32) and c rows, same tiles)
  while (ald(cp0) < 16u) __builtin_amdgcn_s_sleep(2);
  while (ald(cp1) < 16u) __builtin_amdgcn_s_sleep(2);

  int row_a = tile * 16 + m;
  if (row_a >= B) row_a = B - 1;  // B<16 only; dup rows, outputs guarded

  // c-state prefetch (bypass), joined by A batch's single waitcnt
  const float* cb0 = cs + (2 * (tile * 16 + quad * 4)) * MEM + grp * 16 + m;
  const float* cb2 = cb0 + 1024;
  float lc0, rc0, lc1, rc1, lc2, rc2, lc3, rc3;
  asm volatile(
      "global_load_dword %0, %8, off sc0 sc1\n\t"
      "global_load_dword %1, %8, off offset:1024 sc0 sc1\n\t"
      "global_load_dword %2, %8, off offset:2048 sc0 sc1\n\t"
      "global_load_dword %3, %8, off offset:3072 sc0 sc1\n\t"
      "global_load_dword %4, %9, off sc0 sc1\n\t"
      "global_load_dword %5, %9, off offset:1024 sc0 sc1\n\t"
      "global_load_dword %6, %9, off offset:2048 sc0 sc1\n\t"
      "global_load_dword %7, %9, off offset:3072 sc0 sc1"
      : "=v"(lc0), "=v"(rc0), "=v"(lc1), "=v"(rc1),
        "=v"(lc2), "=v"(rc2), "=v"(lc3), "=v"(rc3)
      : "v"(cb0), "v"(cb2) : "memory");

  const unsigned short* arow = hs + row_a * 512 + quad * 8;
  f32x4 a0, a1, a2, a3, a4, a5, a6, a7, a8, a9, a10, a11, a12, a13, a14, a15;
  asm volatile(
      "global_load_dwordx4 %0, %16, off sc0 sc1\n\t"
      "global_load_dwordx4 %1, %16, off offset:64 sc0 sc1\n\t"
      "global_load_dwordx4 %2, %16, off offset:128 sc0 sc1\n\t"
      "global_load_dwordx4 %3, %16, off offset:192 sc0 sc1\n\t"
      "global_load_dwordx4 %4, %16, off offset:256 sc0 sc1\n\t"
      "global_load_dwordx4 %5, %16, off offset:320 sc0 sc1\n\t"
      "global_load_dwordx4 %6, %16, off offset:384 sc0 sc1\n\t"
      "global_load_dwordx4 %7, %16, off offset:448 sc0 sc1\n\t"
      "global_load_dwordx4 %8, %16, off offset:512 sc0 sc1\n\t"
      "global_load_dwordx4 %9, %16, off offset:576 sc0 sc1\n\t"
      "global_load_dwordx4 %10, %16, off offset:640 sc0 sc1\n\t"
      "global_load_dwordx4 %11, %16, off offset:704 sc0 sc1\n\t"
      "global_load_dwordx4 %12, %16, off offset:768 sc0 sc1\n\t"
      "global_load_dwordx4 %13, %16, off offset:832 sc0 sc1\n\t"
      "global_load_dwordx4 %14, %16, off offset:896 sc0 sc1\n\t"
      "global_load_dwordx4 %15, %16, off offset:960 sc0 sc1\n\t"
      "s_waitcnt vmcnt(0)"
      : "=v"(a0), "=v"(a1), "=v"(a2), "=v"(a3), "=v"(a4), "=v"(a5),
        "=v"(a6), "=v"(a7), "=v"(a8), "=v"(a9), "=v"(a10), "=v"(a11),
        "=v"(a12), "=v"(a13), "=v"(a14), "=v"(a15)
      : "v"(arow) : "memory");
  f32x4 af[16] = {a0, a1, a2, a3, a4, a5, a6, a7,
                  a8, a9, a10, a11, a12, a13, a14, a15};

  f32x4 acc0 = {0.f, 0.f, 0.f, 0.f}, acc1 = acc0, acc2 = acc0, acc3 = acc0,
        acc4 = acc0;
#pragma unroll
  for (int kc = 0; kc < 16; kc++) {
    bf16x8 a = __builtin_bit_cast(bf16x8, af[kc]);
    const unsigned short* bp = Wcf + ((kc * 16 + grp) * 5) * 512 + lane * 8;
    bf16x8 b0 = *(const bf16x8*)(bp);
    bf16x8 b1 = *(const bf16x8*)(bp + 512);
    bf16x8 b2 = *(const bf16x8*)(bp + 1024);
    bf16x8 b3 = *(const bf16x8*)(bp + 1536);
    bf16x8 b4 = *(const bf16x8*)(bp + 2048);
    acc0 = __builtin_amdgcn_mfma_f32_16x16x32_bf16(a, b0, acc0, 0, 0, 0);
    acc1 = __builtin_amdgcn_mfma_f32_16x16x32_bf16(a, b1, acc1, 0, 0, 0);
    acc2 = __builtin_amdgcn_mfma_f32_16x16x32_bf16(a, b2, acc2, 0, 0, 0);
    acc3 = __builtin_amdgcn_mfma_f32_16x16x32_bf16(a, b3, acc3, 0, 0, 0);
    acc4 = __builtin_amdgcn_mfma_f32_16x16x32_bf16(a, b4, acc4, 0, 0, 0);
  }
  int col = grp * 16 + m;
  float b0s = bias5[col], b1s = bias5[256 + col], b2s = bias5[512 + col];
  float b3s = bias5[768 + col], b4s = bias5[1024 + col];
  float lcs[4] = {lc0, lc1, lc2, lc3};
  float rcs[4] = {rc0, rc1, rc2, rc3};
#pragma unroll
  for (int reg = 0; reg < 4; reg++) {
    int row = tile * 16 + quad * 4 + reg;
    if (row >= B) continue;
    float u = tanhf(acc0[reg] + b0s);
    float ig = sigf(acc1[reg] + b1s);
    float lf = sigf(acc2[reg] + b2s);
    float rf = sigf(acc3[reg] + b3s);
    float o = sigf(acc4[reg] + b4s);
    float c = ig * u + lf * lcs[reg] + rf * rcs[reg];
    float h = o * tanhf(c);
    st_f32(dc + row * MEM + col, c);
    st_u16(dh + row * MEM + col, f2b(h));
    if (last) st_f32(out + 256 + col, h);
  }
  drain();  // stores at L3 before completion is announced
  if (lane == 0) atomicAdd(cprod, 1u);
}

__global__ __launch_bounds__(NTHR, 1) void k_tree(
    const float* embs, const float* Wx, const float* bx,
    const float* Wl, const float* Wr, const float* emb_last,
    unsigned short* Wcf, unsigned short* Wxf, unsigned short* eb,
    float* bias5, float* cA, float* cB, unsigned short* hA, unsigned short* hB,
    float* out, unsigned* flags, unsigned* gen, unsigned* cnt) {
  const int tid = threadIdx.x;
  const int lane = tid & 63;
  const int wave = tid >> 6;
  const int wave_id = blockIdx.x * 16 + wave;
  const int gtid = blockIdx.x * NTHR + tid;
  const int m = lane & 15, quad = lane >> 4;

  // ---- Phase 0: prep (cached input reads, bypass output stores) ----
  for (int idx = gtid; idx < 1280 * 512; idx += NBLK * NTHR) {  // Wcf
    int f = idx >> 9, r = idx & 511;
    int l8 = r >> 3, j = r & 7;
    int gate = f % 5, t = f / 5;
    int grp = t & 15, kc = t >> 4;
    int k = kc * 32 + ((l8 >> 4) << 3) + j;
    int n = gate * 256 + (grp << 4) + (l8 & 15);
    float v = (k < 256) ? Wl[n * 256 + k] : Wr[n * 256 + (k - 256)];
    st_u16(Wcf + idx, f2b(v));
  }
  for (int idx = gtid; idx < 480 * 512; idx += NBLK * NTHR) {  // Wxf
    int f = idx >> 9, r = idx & 511;
    int l8 = r >> 3, j = r & 7;
    int gate = f % 3, t = f / 3;
    int grp = t & 15, kc = t >> 4;
    int k = kc * 32 + ((l8 >> 4) << 3) + j;
    const int gmap[3] = {0, 1, 3};
    int n = gmap[gate] * 256 + (grp << 4) + (l8 & 15);
    float v = (k < 300) ? Wx[n * 300 + k] : 0.0f;
    st_u16(Wxf + idx, f2b(v));
  }
  for (int idx = gtid; idx < 8192 * 320; idx += NBLK * NTHR) {  // embs->bf16
    int row = idx / 320;
    int k = idx - row * 320;
    st_u16(eb + idx, (k < 300) ? f2b(embs[row * 300 + k]) : 0u);
  }
  if (wave_id < 1280) {  // bias5: one wave per entry, coalesced k-split
    const int map5[5] = {0, 1, 2, 2, 3};
    int g = wave_id >> 8, j = wave_id & 255;
    int wrow = map5[g] * 256 + j;
    const float* w = Wx + wrow * 300;
    float s = 0.0f;
    for (int k = lane; k < 300; k += 64) s += emb_last[k] * w[k];
#pragma unroll
    for (int off = 32; off >= 1; off >>= 1) s += __shfl_down(s, off, 64);
    if (lane == 0) st_f32(bias5 + wave_id, s + bx[wrow]);
  }
  gridbar(flags, gen);  // ONE grid barrier: weights/eb/bias5 ready

  // ---- Phase 1: leaf (2 tasks/wave, same tile: L1 A-reuse) ----
  for (int t = wave_id; t < 8192; t += NWAVE) {
    int tile = t & 511;
    int grp = t >> 9;
    int row_a = tile * 16 + m;
    f32x4 acc0 = {0.f, 0.f, 0.f, 0.f}, acc1 = acc0, acc2 = acc0;
    const unsigned short* arow = eb + row_a * 320 + quad * 8;
#pragma unroll
    for (int kc = 0; kc < 10; kc++) {
      bf16x8 a = *(const bf16x8*)(arow + kc * 32);
      const unsigned short* bp = Wxf + ((kc * 16 + grp) * 3) * 512 + lane * 8;
      bf16x8 b0 = *(const bf16x8*)(bp);
      bf16x8 b1 = *(const bf16x8*)(bp + 512);
      bf16x8 b2 = *(const bf16x8*)(bp + 1024);
      acc0 = __builtin_amdgcn_mfma_f32_16x16x32_bf16(a, b0, acc0, 0, 0, 0);
      acc1 = __builtin_amdgcn_mfma_f32_16x16x32_bf16(a, b1, acc1, 0, 0, 0);
      acc2 = __builtin_amdgcn_mfma_f32_16x16x32_bf16(a, b2, acc2, 0, 0, 0);
    }
    int col = grp * 16 + m;
    float b0 = bx[col], b1 = bx[256 + col], b3 = bx[768 + col];
#pragma unroll
    for (int reg = 0; reg < 4; reg++) {
      int row = tile * 16 + quad * 4 + reg;
      float u = tanhf(acc0[reg] + b0);
      float ig = sigf(acc1[reg] + b1);
      float o = sigf(acc2[reg] + b3);
      float c = ig * u;
      st_f32(cA + row * MEM + col, c);
      st_u16(hA + row * MEM + col, f2b(o * tanhf(c)));
    }
    drain();
    if (lane == 0) atomicAdd(cnt + tile * 16, 1u);  // leaf counters: [0,512)
  }

  // ---- Phase 2: 13 tree levels, dataflow (NO barriers) ----
  const float* cs = cA;
  const unsigned short* hs = hA;
  unsigned* ccons = cnt;        // previous level's counters (leaf: 512 tiles)
  int tiles_prev = 512;
  unsigned* cprod = cnt + 512 * 16;
  int B = 4096, ts = 8, lvl = 0;
  while (true) {
    bool last = (B == 1);
    float* dc;
    unsigned short* dh;
    if (last) {
      dc = out;  // out[col] = c
      dh = hB;   // dummy sink
    } else if ((lvl & 1) == 0) {
      dc = cB; dh = hB;
    } else {
      dc = cA; dh = hA;
    }
    int tiles = (B >= 16) ? (B >> 4) : 1;
    int ntask = tiles * 16;
    for (int t = wave_id; t < ntask; t += NWAVE) {
      int tile = t & (tiles - 1);
      int grp = t >> ts;
      int p0 = 2 * tile, p1 = 2 * tile + 1;
      if (p1 >= tiles_prev) p1 = tiles_prev - 1;
      compose_task(tile, grp, B, last, hs, cs, Wcf, bias5, dc, dh, out,
                   ccons + p0 * 16, ccons + p1 * 16, cprod + tile * 16,
                   m, quad, lane);
    }
    if (last) break;
    cs = dc;
    hs = dh;
    ccons = cprod;
    tiles_prev = tiles;
    cprod += tiles * 16;
    B >>= 1;
    if (ts > 0) ts--;
    lvl++;
  }
  drain();
}

extern "C" void kernel_launch(void* const* d_in, const int* in_sizes, int n_in,
                              void* d_out, int out_size, void* d_ws, size_t ws_size,
                              hipStream_t stream) {
  const float* embs = (const float*)d_in[0];
  const float* Wx = (const float*)d_in[1];
  const float* bx = (const float*)d_in[2];
  const float* Wl = (const float*)d_in[3];
  const float* Wr = (const float*)d_in[4];
  const float* emb_table = (const float*)d_in[5];
  float* out = (float*)d_out;

  // Workspace: [0,1K) gen | [4K,36K) flags | [40K,~106K) tile counters
  // (64B stride, 1027 entries) | data from 128K (~25MB)
  unsigned* gen = (unsigned*)d_ws;
  unsigned* flags = (unsigned*)((char*)d_ws + 4096);
  unsigned* cnt = (unsigned*)((char*)d_ws + 40960);
  float* base = (float*)((char*)d_ws + 131072);
  float* cA = base;                              // 8192*256 f32
  float* cB = cA + 8192 * 256;                   // 4096*256 f32
  float* bias5 = cB + 4096 * 256;                // 1280 f32
  unsigned short* hA = (unsigned short*)(bias5 + 1280);  // 8192*256 bf16
  unsigned short* hB = hA + 8192 * 256;                  // 4096*256 bf16
  unsigned short* Wcf = hB + 4096 * 256;                 // 1280*512
  unsigned short* Wxf = Wcf + 1280 * 512;                // 480*512
  unsigned short* eb = Wxf + 480 * 512;                  // 8192*320

  hipMemsetAsync(d_ws, 0, 131072, stream);  // zero gen+flags+counters

  k_tree<<<NBLK, NTHR, 0, stream>>>(
      embs, Wx, bx, Wl, Wr, emb_table + (in_sizes[5] - 300),
      Wcf, Wxf, eb, bias5, cA, cB, hA, hB, out, flags, gen, cnt);
}